// Round 4
// baseline (740.425 us; speedup 1.0000x reference)
//
#include <hip/hip_runtime.h>
#include <cstdint>
#include <cstddef>

typedef __bf16 bf16_t;
typedef __bf16 bf16x8 __attribute__((ext_vector_type(8)));
typedef __bf16 bf16x4 __attribute__((ext_vector_type(4)));
typedef float floatx4 __attribute__((ext_vector_type(4)));

// ---------------- helpers ----------------
__device__ __forceinline__ float wred_sum(float v) {
#pragma unroll
  for (int off = 32; off > 0; off >>= 1) v += __shfl_xor(v, off);
  return v;
}
__device__ __forceinline__ void async16(const void* g, void* l) {
  __builtin_amdgcn_global_load_lds((const __attribute__((address_space(1))) void*)g,
                                   (__attribute__((address_space(3))) void*)l, 16, 0, 0);
}

// ---------------- 256x256 8-wave GEMM, BK=32, triple-buffer, counted vmcnt ----------------
// T2: XOR-swizzled LDS (pre-swizzled global source, lane-constant read chunk).
// T3: 2 phases/K-tile {stage 2 gload_lds || 8-12 ds_read_b128 -> barrier -> 16 MFMA -> barrier}.
// T4: loads for tile t issued during t-2; end-of-tile s_waitcnt vmcnt(4) (never 0 except tail)
//     + RAW s_barrier => tile t+1 collectively resident, t+2 stays in flight.
// T5: setprio(1) around MFMA clusters.  T1: XCD-aware block swizzle (nwg % 8 == 0).
// Per-wave 128x64 output (acc[8][4] floatx4 = 128 VGPR). 96 KB LDS -> 1 block/CU.
// Assumes M % 256 == 0, N % 256 == 0 (pad B), K % 32 == 0, K/32 >= 3.
// MODE: 1 = bf16 out | 5 = GeGLU epilogue (interleaved a/gate cols) -> bf16 y [M x 1365]
template <int MODE>
__global__ __launch_bounds__(512, 2) void st_gemm8(
    const bf16_t* __restrict__ A, const bf16_t* __restrict__ B, void* Cp,
    int M, int N, int K, int lda, int ldb, int ldc) {
  __shared__ bf16_t sA[3][256 * 32];  // 48 KB
  __shared__ bf16_t sB[3][256 * 32];  // 48 KB
  const int tid = threadIdx.x;
  const int lane = tid & 63, wave = tid >> 6;
  const int wr = wave >> 2, wc = wave & 3;       // 2M x 4N waves
  const int cl = lane & 15, cfc = lane >> 4;
  // T1 XCD swizzle (requires nwg % 8 == 0)
  const int gx = gridDim.x;
  const int flat = blockIdx.y * gx + blockIdx.x;
  const int qq = (gx * gridDim.y) >> 3;
  const int swz = (flat & 7) * qq + (flat >> 3);
  const int bm = swz % gx, bn = swz / gx;

  // staging: slot = i*512+tid -> LDS byte slot*16 (linear dest, wave-uniform base+lane*16).
  // 128-B LDS line = 8 x 16B chunks; stored chunk w8 holds nominal chunk nfc = w8 ^ (line&7),
  // nominal (row, kchunk): row = 2*line + (nfc>>2), kchunk = nfc&3  (2 rows of 64B per line).
  const bf16_t* aSg[2];
  const bf16_t* bSg[2];
  int sOff[2];
#pragma unroll
  for (int i = 0; i < 2; ++i) {
    int slot = i * 512 + tid;
    int line = slot >> 3, w8 = slot & 7;
    int nfc = w8 ^ (line & 7);
    int row = line * 2 + (nfc >> 2), c = nfc & 3;
    aSg[i] = A + (size_t)(bm * 256 + row) * lda + c * 8;
    bSg[i] = B + (size_t)(bn * 256 + row) * ldb + c * 8;
    sOff[i] = slot * 16;
  }
  // fragment read: row r = tile_r + cl, k-chunk cfc. line = r>>1; chunk = ((r&1)<<2|cfc) ^ (line&7).
  // For 16-row-aligned tile_r: (line&7) = cl>>1, (r&1) = cl&1  -> chunk is LANE-CONSTANT.
  const int fch = (((((cl & 1) << 2) | cfc) ^ (cl >> 1))) * 16;
  const int aBase = wr * 8192 + (cl >> 1) * 128 + fch;  // + m*1024
  const int bBase = wc * 4096 + (cl >> 1) * 128 + fch;  // + n*1024

  floatx4 acc[8][4];
#pragma unroll
  for (int m = 0; m < 8; ++m)
#pragma unroll
    for (int n = 0; n < 4; ++n) acc[m][n] = floatx4{0.f, 0.f, 0.f, 0.f};

  // prologue: stage tiles 0 and 1; wait tile 0 (vmcnt(4): tile 1's 4 loads stay in flight)
  async16(aSg[0], (char*)sA[0] + sOff[0]);
  async16(aSg[1], (char*)sA[0] + sOff[1]);
  async16(bSg[0], (char*)sB[0] + sOff[0]);
  async16(bSg[1], (char*)sB[0] + sOff[1]);
  async16(aSg[0] + 32, (char*)sA[1] + sOff[0]);
  async16(aSg[1] + 32, (char*)sA[1] + sOff[1]);
  async16(bSg[0] + 32, (char*)sB[1] + sOff[0]);
  async16(bSg[1] + 32, (char*)sB[1] + sOff[1]);
  __builtin_amdgcn_sched_barrier(0);
  asm volatile("s_waitcnt vmcnt(4)" ::: "memory");
  __builtin_amdgcn_s_barrier();

  const int NT = K >> 5;
  int bcur = 0, bnx = 2;
#pragma unroll 1
  for (int t = 0; t < NT; ++t) {
    const char* sAc = (const char*)sA[bcur];
    const char* sBc = (const char*)sB[bcur];
    char* sAn = (char*)sA[bnx];
    char* sBn = (char*)sB[bnx];
    const int kt2 = (t + 2) << 5;
    const bool pf = (t + 2) < NT;
    bf16x8 af[4], bv[4];
    // ---- phase 0: stage A(t+2); read af(m=0..3) + bv(all 4); MFMA acc[0..3][*]
    if (pf) {
      async16(aSg[0] + kt2, sAn + sOff[0]);
      async16(aSg[1] + kt2, sAn + sOff[1]);
    }
#pragma unroll
    for (int m = 0; m < 4; ++m) af[m] = *(const bf16x8*)(sAc + aBase + m * 1024);
#pragma unroll
    for (int n = 0; n < 4; ++n) bv[n] = *(const bf16x8*)(sBc + bBase + n * 1024);
    __builtin_amdgcn_sched_barrier(0);
    __builtin_amdgcn_s_barrier();
    __builtin_amdgcn_s_setprio(1);
#pragma unroll
    for (int m = 0; m < 4; ++m)
#pragma unroll
      for (int n = 0; n < 4; ++n)
        acc[m][n] = __builtin_amdgcn_mfma_f32_16x16x32_bf16(af[m], bv[n], acc[m][n], 0, 0, 0);
    __builtin_amdgcn_s_setprio(0);
    __builtin_amdgcn_sched_barrier(0);
    __builtin_amdgcn_s_barrier();
    // ---- phase 1: stage B(t+2); read af(m=4..7), reuse bv; MFMA acc[4..7][*]
    if (pf) {
      async16(bSg[0] + kt2, sBn + sOff[0]);
      async16(bSg[1] + kt2, sBn + sOff[1]);
    }
#pragma unroll
    for (int m = 0; m < 4; ++m) af[m] = *(const bf16x8*)(sAc + aBase + (m + 4) * 1024);
    __builtin_amdgcn_sched_barrier(0);
    __builtin_amdgcn_s_barrier();
    __builtin_amdgcn_s_setprio(1);
#pragma unroll
    for (int m = 0; m < 4; ++m)
#pragma unroll
      for (int n = 0; n < 4; ++n)
        acc[m + 4][n] = __builtin_amdgcn_mfma_f32_16x16x32_bf16(af[m], bv[n], acc[m + 4][n], 0, 0, 0);
    __builtin_amdgcn_s_setprio(0);
    __builtin_amdgcn_sched_barrier(0);
    // ---- end of tile: counted wait (t+1 resident; t+2 in flight), tail drains once
    if (t < NT - 1) {
      if (t == NT - 2) asm volatile("s_waitcnt vmcnt(0)" ::: "memory");
      else             asm volatile("s_waitcnt vmcnt(4)" ::: "memory");
    }
    __builtin_amdgcn_s_barrier();
    bcur = (bcur == 2) ? 0 : bcur + 1;
    bnx = (bnx == 2) ? 0 : bnx + 1;
  }

  // ---- epilogue ----
  const int rowB = bm * 256 + wr * 128 + cfc * 4;
  if (MODE == 1) {
    bf16_t* yb = (bf16_t*)Cp;
    const int colB = bn * 256 + wc * 64 + cl;
#pragma unroll
    for (int m = 0; m < 8; ++m)
#pragma unroll
      for (int n = 0; n < 4; ++n) {
        size_t base = (size_t)(rowB + m * 16) * ldc + colB + n * 16;
#pragma unroll
        for (int r = 0; r < 4; ++r) yb[base + (size_t)r * ldc] = (bf16_t)acc[m][n][r];
      }
  } else {  // MODE 5: GeGLU (frag pairs: 2p = a, 2p+1 = gate), tanh-form gelu
    bf16_t* yb = (bf16_t*)Cp;
    const int cg0 = ((bn * 256 + wc * 64) >> 5) * 16;
#pragma unroll
    for (int m = 0; m < 8; ++m)
#pragma unroll
      for (int p = 0; p < 2; ++p) {
        int c = cg0 + p * 16 + cl;
        if (c >= 1365) continue;
#pragma unroll
        for (int r = 0; r < 4; ++r) {
          int row = rowB + m * 16 + r;
          float a = acc[m][2 * p][r];
          float gt = acc[m][2 * p + 1][r];
          float zz = gt * (0.7978845608f + 0.03567740814f * gt * gt);
          float u = __builtin_exp2f(-2.8853900817779268f * zz);
          float y = a * gt / (1.f + u);
          yb[(size_t)row * ldc + c] = (bf16_t)y;
        }
      }
  }
}

// ---------------- generic batched bf16 GEMM (m97 structure, R10 VALU diet) ----------------
// Still used for the N=512 GEMMs (wo x2, wout) where 256^2 tiles would idle half the GPU.
// MODE: 2 f32 out + resid | 3 resid + spatial->temporal permuted f32 write |
//       4 resid + temporal->spatial permuted f32 write + bf16 dual write
template <int MODE>
__global__ __launch_bounds__(256) void st_gemm(
    const bf16_t* __restrict__ A, const bf16_t* __restrict__ B, void* Cp, void* Cp2,
    const float* Res, int M, int N, int K, int lda, int ldb, int ldc) {
  __shared__ bf16_t sA[128 * 32];
  __shared__ bf16_t sB[128 * 32];
  const int tid = threadIdx.x;
  const int bm = blockIdx.x, bn = blockIdx.y;
  const int lane = tid & 63;
  const int wave = tid >> 6;
  const int wm = (wave >> 1) * 64, wn = (wave & 1) * 64;
  const int rowf = lane & 15, qc = lane >> 4;
  const int fco = (qc ^ ((rowf >> 1) & 3)) * 8;

  const bf16_t* aSrc[2];
  const bf16_t* bSrc[2];
  char* aDst[2];
  char* bDst[2];
#pragma unroll
  for (int it = 0; it < 2; ++it) {
    int slot = it * 256 + tid;
    int mi = slot >> 2, kc = slot & 3;
    int cs = kc ^ ((mi >> 1) & 3);
    int ar = bm * 128 + mi; if (ar > M - 1) ar = M - 1;
    int br = bn * 128 + mi; if (br > N - 1) br = N - 1;
    aSrc[it] = A + (size_t)ar * lda + cs * 8;
    bSrc[it] = B + (size_t)br * ldb + cs * 8;
    aDst[it] = (char*)sA + slot * 16;
    bDst[it] = (char*)sB + slot * 16;
  }

  floatx4 acc[4][4];
#pragma unroll
  for (int i = 0; i < 4; ++i)
#pragma unroll
    for (int j = 0; j < 4; ++j) acc[i][j] = floatx4{0.f, 0.f, 0.f, 0.f};

  for (int kt = 0; kt < K; kt += 32) {
#pragma unroll
    for (int it = 0; it < 2; ++it) {
      async16(aSrc[it] + kt, aDst[it]);
      async16(bSrc[it] + kt, bDst[it]);
    }
    __syncthreads();
    bf16x8 af[4], bv[4];
#pragma unroll
    for (int i = 0; i < 4; ++i) {
      af[i] = *(const bf16x8*)(sA + (wm + i * 16 + rowf) * 32 + fco);
      bv[i] = *(const bf16x8*)(sB + (wn + i * 16 + rowf) * 32 + fco);
    }
#pragma unroll
    for (int i = 0; i < 4; ++i)
#pragma unroll
      for (int j = 0; j < 4; ++j)
        acc[i][j] = __builtin_amdgcn_mfma_f32_16x16x32_bf16(af[i], bv[j], acc[i][j], 0, 0, 0);
    __syncthreads();
  }

  const int cl = lane & 15;
  const int rowBase = bm * 128 + wm + (lane >> 4) * 4;
  const int colBase = bn * 128 + wn + cl;
#pragma unroll
  for (int i = 0; i < 4; ++i) {
#pragma unroll
    for (int j = 0; j < 4; ++j) {
      int col = colBase + j * 16;
      if (col >= N) continue;
#pragma unroll
      for (int r = 0; r < 4; ++r) {
        int row = rowBase + i * 16 + r;
        if (row >= M) continue;
        long long inidx = (long long)row * ldc + col;
        float v = acc[i][j][r] + Res[inidx];
        if (MODE == 2) { ((float*)Cp)[inidx] = v; }
        else if (MODE == 3) {
          int orow = (row & ~8191) | ((row & 1023) << 3) | ((row >> 10) & 7);
          ((float*)Cp)[(long long)orow * ldc + col] = v;
        } else if (MODE == 4) {
          int orow = (row & ~8191) | ((row & 7) << 10) | ((row >> 3) & 1023);
          long long oidx = (long long)orow * ldc + col;
          ((float*)Cp)[oidx] = v;
          ((bf16_t*)Cp2)[oidx] = (bf16_t)v;
        }
      }
    }
  }
}

// ---------------- tiled fp32 transpose (R x C) -> (C x R), batched ----------------
__global__ __launch_bounds__(256) void st_transpose2d(
    const float* __restrict__ in, float* __restrict__ out, int R, int Cc,
    long long inb, long long outb) {
  __shared__ float tile[32][33];
  const int ct = blockIdx.x, rt = blockIdx.y, b = blockIdx.z;
  in += (long long)b * inb;
  out += (long long)b * outb;
  const int tx = threadIdx.x & 31, ty = threadIdx.x >> 5;
#pragma unroll
  for (int k = 0; k < 4; ++k) {
    int r = rt * 32 + ty + k * 8;
    int c = ct * 32 + tx;
    tile[ty + k * 8][tx] = in[(size_t)r * Cc + c];
  }
  __syncthreads();
#pragma unroll
  for (int k = 0; k < 4; ++k) {
    int c = ct * 32 + ty + k * 8;
    int r = rt * 32 + tx;
    out[(size_t)c * R + r] = tile[tx][ty + k * 8];
  }
}

// ---------------- weight transpose fp32 (K x N) -> bf16 (N x Kpad) ----------------
__global__ void st_wtrans(const float* __restrict__ src, bf16_t* __restrict__ dst,
                          int K, int Kpad, int N, int srcld, int coloff, long total) {
  long idx = (long)blockIdx.x * 256 + threadIdx.x;
  if (idx >= total) return;
  int kp = (int)(idx % Kpad);
  int n = (int)(idx / Kpad);
  float v = (kp < K) ? src[(size_t)kp * srcld + coloff + n] : 0.f;
  dst[idx] = (bf16_t)v;
}

// winT GeGLU-interleave: dst row n: block=n>>5, w=n&31;
// c = block*16 + (w&15); a if (n>>4)&1==0 else gate (srccol += 1365); pad rows -> 0
__global__ void st_wtrans_geglu(const float* __restrict__ src, bf16_t* __restrict__ dst,
                                long total) {
  long idx = (long)blockIdx.x * 256 + threadIdx.x;
  if (idx >= total) return;
  int kp = (int)(idx & 511);
  int n = (int)(idx >> 9);
  int c = ((n >> 5) << 4) + (n & 15);
  float v = 0.f;
  if (c < 1365) {
    int srccol = c + (((n >> 4) & 1) ? 1365 : 0);
    v = src[(size_t)kp * 2730 + srccol];
  }
  dst[idx] = (bf16_t)v;
}

// ---------------- CPB MLP tables ----------------
// 2d table: f32, pre-scaled by 8 so it can serve directly as the MFMA C-init:
// exp(0.125*s + b) == exp2((s + 8b) * 0.125 * log2(e))
__global__ __launch_bounds__(256) void st_cpb(
    const float* __restrict__ w1, const float* __restrict__ b1,
    const float* __restrict__ w2, const float* __restrict__ b2,
    const float* __restrict__ w3, const float* __restrict__ b3,
    float* __restrict__ tab2d, float* __restrict__ tab1d, int two_d) {
  const int pos = blockIdx.x, t = threadIdx.x;
  float r0, r1 = 0.f;
  if (two_d) { r0 = (float)(pos / 63 - 31); r1 = (float)(pos % 63 - 31); }
  else { r0 = (float)(pos - 7); }
  __shared__ float sh[256];
  float h = r0 * w1[t] + (two_d ? r1 * w1[256 + t] : 0.f) + b1[t];
  h = h / (1.f + expf(-h));
  sh[t] = h;
  __syncthreads();
  float h2 = b2[t];
  for (int j = 0; j < 256; ++j) h2 += sh[j] * w2[j * 256 + t];
  h2 = h2 / (1.f + expf(-h2));
  __syncthreads();
  sh[t] = h2;
  __syncthreads();
  if (t < 8) {
    float o = b3[t];
    for (int j = 0; j < 256; ++j) o += sh[j] * w3[j * 8 + t];
    if (two_d) tab2d[t * 4000 + pos] = o * 8.0f;
    else tab1d[t * 15 + pos] = o;
  }
}

// ---------------- RMS norm -> bf16 ----------------
__global__ __launch_bounds__(256) void st_rmsnorm(const float* __restrict__ x,
                                                  const float* __restrict__ gamma,
                                                  bf16_t* __restrict__ y) {
  const int token = blockIdx.x * 4 + (threadIdx.x >> 6);
  const int lane = threadIdx.x & 63;
  const float* xr = x + (size_t)token * 512;
  float v[8];
  float ss = 0.f;
#pragma unroll
  for (int k = 0; k < 8; ++k) { v[k] = xr[k * 64 + lane]; ss += v[k] * v[k]; }
  ss = wred_sum(ss);
  const float r = 22.627416998f / fmaxf(sqrtf(ss), 1e-12f);
  bf16_t* yr = y + (size_t)token * 512;
#pragma unroll
  for (int k = 0; k < 8; ++k) yr[k * 64 + lane] = (bf16_t)(v[k] * r * gamma[k * 64 + lane]);
}

// ---------------- V transpose: qkv -> vT[(bf*8+h)][d][j] ----------------
__global__ __launch_bounds__(256) void st_vtrans(const bf16_t* __restrict__ qkv,
                                                 bf16_t* __restrict__ vT) {
  __shared__ float tile[32][33];
  const int jt = blockIdx.x, dt = blockIdx.y, z = blockIdx.z;
  const int bf = z >> 3, h = z & 7;
  const int tx = threadIdx.x & 31, ty = threadIdx.x >> 5;
#pragma unroll
  for (int k = 0; k < 4; ++k) {
    int j = jt * 32 + ty + k * 8;
    int d = dt * 32 + tx;
    tile[ty + k * 8][tx] = (float)qkv[((size_t)(bf * 1024 + j)) * 1536 + 1024 + h * 64 + d];
  }
  __syncthreads();
#pragma unroll
  for (int k = 0; k < 4; ++k) {
    int d = dt * 32 + ty + k * 8;
    int j = jt * 32 + tx;
    vT[((size_t)z * 64 + d) * 1024 + j] = (bf16_t)tile[tx][ty + k * 8];
  }
}

// ---------------- fused flash spatial attention (R9 structure) ----------------
__global__ __launch_bounds__(256, 4) void st_flash(
    const bf16_t* __restrict__ qkv, const bf16_t* __restrict__ vT,
    const float* __restrict__ tab2f, bf16_t* __restrict__ ob) {
  __shared__ __align__(16) bf16_t ldsK[2][32 * 64];   // [j][d] rows 128B, XOR-swz (row&7)
  __shared__ __align__(16) bf16_t ldsV[2][64 * 32];   // [d][j] rows 64B,  XOR-swz (row&3)
  __shared__ __align__(16) bf16_t ldsP[4 * 32 * 32];  // per-wave 32i x 32j, rows 64B
  __shared__ __align__(16) float ldsT[2208];          // f32 bias slice (pre-scaled x8)
  const int qtile = blockIdx.x;  // 0..7, 128 q rows each
  const int z = blockIdx.y;
  const int bf = z >> 3, h = z & 7;
  const int tid = threadIdx.x;
  const int lane = tid & 63, wave = tid >> 6;
  const int cl = lane & 15, g = lane >> 4;
  const size_t qkvBase = (size_t)bf * 1024 * 1536 + h * 64;
  const int eoff = (qtile * 252) & ~3;
  const bf16_t* Kp = qkv + qkvBase + 512;
  const bf16_t* Vp = vT + (size_t)z * 65536;

#pragma unroll
  for (int it = 0; it < 3; ++it) {
    int s = it * 256 + tid;
    if (s < 552) async16(tab2f + h * 4000 + eoff + s * 4, (char*)ldsT + s * 16);
  }
  {
    int row = tid >> 3, c = tid & 7, cs = c ^ (row & 7);
    async16(Kp + (size_t)row * 1536 + cs * 8, (char*)ldsK[0] + tid * 16);
    int rv = tid >> 2, cv = tid & 3, csv = cv ^ (rv & 3);
    async16(Vp + (size_t)rv * 1024 + csv * 8, (char*)ldsV[0] + tid * 16);
  }
  bf16x8 aq[2][2];
#pragma unroll
  for (int it = 0; it < 2; ++it)
#pragma unroll
    for (int ks = 0; ks < 2; ++ks) {
      int row = qtile * 128 + wave * 32 + it * 16 + cl;
      aq[it][ks] = *(const bf16x8*)(qkv + qkvBase + (size_t)row * 1536 + (ks * 4 + g) * 8);
    }
  __syncthreads();

  int fiB[2];
#pragma unroll
  for (int it = 0; it < 2; ++it) {
    int i = qtile * 128 + wave * 32 + it * 16 + cl;
    fiB[it] = (i >> 5) * 63 + (i & 31) + 1984 - eoff;
  }
  float lsum[2] = {0.f, 0.f};
  floatx4 oacc[4][2];
#pragma unroll
  for (int dt = 0; dt < 4; ++dt)
#pragma unroll
    for (int it = 0; it < 2; ++it) oacc[dt][it] = floatx4{0.f, 0.f, 0.f, 0.f};

  bf16_t* ldsPw = ldsP + wave * (32 * 32);
  const float SC = 0.18033688011112042f;  // 0.125 * log2(e)

#pragma unroll 2
  for (int t = 0; t < 32; ++t) {
    const int p = t & 1;
    if (t < 31) {
      const int j1 = (t + 1) * 32;
      int row = tid >> 3, c = tid & 7, cs = c ^ (row & 7);
      async16(Kp + (size_t)(j1 + row) * 1536 + cs * 8, (char*)ldsK[p ^ 1] + tid * 16);
      int rv = tid >> 2, cv = tid & 3, csv = cv ^ (rv & 3);
      async16(Vp + (size_t)rv * 1024 + j1 + csv * 8, (char*)ldsV[p ^ 1] + tid * 16);
    }
    const int j0 = t * 32;
#pragma unroll
    for (int jt = 0; jt < 2; ++jt) {
      int jb = j0 + jt * 16 + g * 4;
      int fjb = (jb >> 5) * 63 + (jb & 31);
      floatx4 sj[2];
#pragma unroll
      for (int it = 0; it < 2; ++it) {
        int idx0 = fiB[it] - fjb;
        sj[it] = floatx4{ldsT[idx0], ldsT[idx0 - 1], ldsT[idx0 - 2], ldsT[idx0 - 3]};
      }
#pragma unroll
      for (int ks = 0; ks < 2; ++ks) {
        int row = jt * 16 + cl;
        bf16x8 kf = *(const bf16x8*)(ldsK[p] + row * 64 + (((ks * 4 + g) ^ (row & 7))) * 8);
#pragma unroll
        for (int it = 0; it < 2; ++it)
          sj[it] = __builtin_amdgcn_mfma_f32_16x16x32_bf16(kf, aq[it][ks], sj[it], 0, 0, 0);
      }
      int gg = jt * 2 + (g >> 1);
#pragma unroll
      for (int it = 0; it < 2; ++it) {
        float e0 = __builtin_exp2f(sj[it][0] * SC);
        float e1 = __builtin_exp2f(sj[it][1] * SC);
        float e2 = __builtin_exp2f(sj[it][2] * SC);
        float e3 = __builtin_exp2f(sj[it][3] * SC);
        lsum[it] += (e0 + e1) + (e2 + e3);
        bf16x4 pv = {(bf16_t)e0, (bf16_t)e1, (bf16_t)e2, (bf16_t)e3};
        *(bf16x4*)((char*)ldsPw + (it * 16 + cl) * 64 +
                   ((gg ^ (cl & 3)) * 16 + (g & 1) * 8)) = pv;
      }
    }
    {
      bf16x8 pB[2];
#pragma unroll
      for (int it = 0; it < 2; ++it)
        pB[it] = *(const bf16x8*)((char*)ldsPw + (it * 16 + cl) * 64 + ((g ^ (cl & 3)) * 16));
#pragma unroll
      for (int dt = 0; dt < 4; ++dt) {
        int row = dt * 16 + cl;
        bf16x8 vf = *(const bf16x8*)(ldsV[p] + row * 32 + ((g ^ (row & 3)) * 8));
#pragma unroll
        for (int it = 0; it < 2; ++it)
          oacc[dt][it] = __builtin_amdgcn_mfma_f32_16x16x32_bf16(vf, pB[it], oacc[dt][it], 0, 0, 0);
      }
    }
    __syncthreads();
  }
  float inv[2];
#pragma unroll
  for (int it = 0; it < 2; ++it) {
    float s = lsum[it];
    s += __shfl_xor(s, 16);
    s += __shfl_xor(s, 32);
    inv[it] = 1.f / s;
  }
#pragma unroll
  for (int it = 0; it < 2; ++it) {
    int i = qtile * 128 + wave * 32 + it * 16 + cl;
    size_t base = ((size_t)bf * 1024 + i) * 512 + h * 64 + g * 4;
#pragma unroll
    for (int dt = 0; dt < 4; ++dt) {
      bf16x4 ov = {(bf16_t)(oacc[dt][it][0] * inv[it]), (bf16_t)(oacc[dt][it][1] * inv[it]),
                   (bf16_t)(oacc[dt][it][2] * inv[it]), (bf16_t)(oacc[dt][it][3] * inv[it])};
      *(bf16x4*)(ob + base + dt * 16) = ov;
    }
  }
}

// ---------------- temporal attention (seq=8), log-transpose reduce ----------------
__global__ __launch_bounds__(256) void st_tattn2(const bf16_t* __restrict__ qkv,
                                                 const float* __restrict__ tabf,
                                                 bf16_t* __restrict__ o) {
  const int wg = blockIdx.x * 4 + (threadIdx.x >> 6);
  const int bhw = wg >> 3, head = wg & 7;
  const int lane = threadIdx.x & 63;
  const size_t base = (size_t)bhw * 8 * 1536 + head * 64 + lane;
  float q[8], k[8], v[8];
#pragma unroll
  for (int f = 0; f < 8; ++f) {
    q[f] = (float)qkv[base + (size_t)f * 1536];
    k[f] = (float)qkv[base + (size_t)f * 1536 + 512];
    v[f] = (float)qkv[base + (size_t)f * 1536 + 1024];
  }
  float p[64];
#pragma unroll
  for (int i = 0; i < 8; ++i)
#pragma unroll
    for (int j = 0; j < 8; ++j) p[i * 8 + j] = q[i] * k[j];
#pragma unroll
  for (int st = 32; st >= 1; st >>= 1) {
    const bool hi = (lane & st) != 0;
#pragma unroll
    for (int m = 0; m < st; ++m) {
      float give = hi ? p[m] : p[m + st];
      float keep = hi ? p[m + st] : p[m];
      p[m] = keep + __shfl_xor(give, st);
    }
  }
  const int i = lane >> 3, j = lane & 7;
  float e = __expf(p[0] * 0.125f + tabf[head * 15 + i - j + 7]);
  float sm = e;
  sm += __shfl_xor(sm, 1);
  sm += __shfl_xor(sm, 2);
  sm += __shfl_xor(sm, 4);
  const float prob = e / sm;
  float acc[8];
#pragma unroll
  for (int ii = 0; ii < 8; ++ii) acc[ii] = 0.f;
#pragma unroll
  for (int ii = 0; ii < 8; ++ii)
#pragma unroll
    for (int jj = 0; jj < 8; ++jj)
      acc[ii] += __shfl(prob, ii * 8 + jj) * v[jj];
#pragma unroll
  for (int ii = 0; ii < 8; ++ii)
    o[(size_t)(bhw * 8 + ii) * 512 + head * 64 + lane] = (bf16_t)acc[ii];
}

// ---------------- temporal shift + RMS on pre-activated y -> ynb (K padded 1376) ----------------
__global__ __launch_bounds__(256) void st_glu(const bf16_t* __restrict__ y,
                                              const float* __restrict__ gamma,
                                              bf16_t* __restrict__ yn) {
  const int t = blockIdx.x;
  const int tid = threadIdx.x;
  const int f = (t >> 10) & 7;
  float yv[6];
  float ss = 0.f;
#pragma unroll
  for (int kk = 0; kk < 6; ++kk) {
    int c = kk * 256 + tid;
    float v = 0.f;
    if (c < 1365) {
      long src = t;
      bool valid = true;
      if (c >= 683) { if (f == 0) valid = false; else src = t - 1024; }
      if (valid) v = (float)y[src * 1365 + c];
    }
    yv[kk] = v;
    ss += v * v;
  }
  __shared__ float red[4];
  ss = wred_sum(ss);
  if ((tid & 63) == 0) red[tid >> 6] = ss;
  __syncthreads();
  ss = red[0] + red[1] + red[2] + red[3];
  const float r = sqrtf(1365.f) / fmaxf(sqrtf(ss), 1e-12f);
#pragma unroll
  for (int kk = 0; kk < 6; ++kk) {
    int c = kk * 256 + tid;
    if (c < 1365) yn[(size_t)t * 1376 + c] = (bf16_t)(yv[kk] * r * gamma[c]);
  }
  if (tid < 11) yn[(size_t)t * 1376 + 1365 + tid] = (bf16_t)0.f;
}

// ---------------- launcher ----------------
extern "C" void kernel_launch(void* const* d_in, const int* in_sizes, int n_in,
                              void* d_out, int out_size, void* d_ws, size_t ws_size,
                              hipStream_t stream) {
  const float* x        = (const float*)d_in[0];
  const float* sa_gamma = (const float*)d_in[1];
  const float* sa_wq    = (const float*)d_in[2];
  const float* sa_wkv   = (const float*)d_in[3];
  const float* sa_wo    = (const float*)d_in[4];
  const float* ta_gamma = (const float*)d_in[5];
  const float* ta_wq    = (const float*)d_in[6];
  const float* ta_wkv   = (const float*)d_in[7];
  const float* ta_wo    = (const float*)d_in[8];
  const float* sp_w1 = (const float*)d_in[9];
  const float* sp_b1 = (const float*)d_in[10];
  const float* sp_w2 = (const float*)d_in[11];
  const float* sp_b2 = (const float*)d_in[12];
  const float* sp_w3 = (const float*)d_in[13];
  const float* sp_b3 = (const float*)d_in[14];
  const float* tp_w1 = (const float*)d_in[15];
  const float* tp_b1 = (const float*)d_in[16];
  const float* tp_w2 = (const float*)d_in[17];
  const float* tp_b2 = (const float*)d_in[18];
  const float* tp_w3 = (const float*)d_in[19];
  const float* tp_b3 = (const float*)d_in[20];
  const float* ff_win   = (const float*)d_in[21];
  const float* ff_gamma = (const float*)d_in[22];
  const float* ff_wout  = (const float*)d_in[23];
  float* outp = (float*)d_out;

  char* ws = (char*)d_ws;
  size_t off = 0;
  auto alloc = [&](size_t bytes) -> char* {
    char* p = ws + off;
    off += (bytes + 255) & ~(size_t)255;
    return p;
  };
  const long T = 16384;
  float*  xs  = (float*)alloc((size_t)T * 512 * 4);    // residual stream
  bf16_t* xn  = (bf16_t*)alloc((size_t)T * 512 * 2);   // normed input | ob_s
  char*   R2  = alloc((size_t)T * 1536 * 2);           // qkv | FF: y (16384x1365 bf16)
  char*   R3  = alloc((size_t)T * 1536 * 2);           // vT (16M) | xt (33.5M)
  char*   R4  = alloc((size_t)T * 1376 * 2);           // ob_t (16M) | ynb (45M)
  bf16_t* wqkvT_sa = (bf16_t*)alloc(1536ULL * 512 * 2);
  bf16_t* woT_sa   = (bf16_t*)alloc(512ULL * 512 * 2);
  bf16_t* wqkvT_ta = (bf16_t*)alloc(1536ULL * 512 * 2);
  bf16_t* woT_ta   = (bf16_t*)alloc(512ULL * 512 * 2);
  bf16_t* winT  = (bf16_t*)alloc(2816ULL * 512 * 2);   // GeGLU-interleaved, padded to 2816
  bf16_t* woutT = (bf16_t*)alloc(512ULL * 1376 * 2);
  float*  tab2f = (float*)alloc(8 * 4000 * 4);         // f32 spatial bias (x8 pre-scale)
  float*  tabf  = (float*)alloc(8 * 15 * 4);

  bf16_t* qkv  = (bf16_t*)R2;
  bf16_t* ybuf = (bf16_t*)R2;    // FF pre-activated hidden (qkv dead)
  bf16_t* vT   = (bf16_t*)R3;
  float*  xt   = (float*)R3;     // temporal residual (vT dead after flash)
  bf16_t* ob_s = xn;             // spatial attn out reuses xn region
  bf16_t* ob_t = (bf16_t*)R4;    // temporal attn out
  bf16_t* ynb  = (bf16_t*)R4;    // normed FF hidden (ob_t dead)

  // 1) input: per b transpose (512 x 8192) -> (8192 x 512)
  st_transpose2d<<<dim3(256, 16, 2), 256, 0, stream>>>(x, xs, 512, 8192,
                                                       (long long)512 * 8192, (long long)512 * 8192);
  // 2) weight transposes
  auto wt = [&](const float* src, bf16_t* dst, int K, int Kpad, int N, int srcld, int coloff) {
    long tot = (long)N * Kpad;
    st_wtrans<<<dim3((tot + 255) / 256), 256, 0, stream>>>(src, dst, K, Kpad, N, srcld, coloff, tot);
  };
  wt(sa_wq, wqkvT_sa, 512, 512, 512, 512, 0);
  wt(sa_wkv, wqkvT_sa + 512 * 512, 512, 512, 1024, 1024, 0);
  wt(sa_wo, woT_sa, 512, 512, 512, 512, 0);
  wt(ta_wq, wqkvT_ta, 512, 512, 512, 512, 0);
  wt(ta_wkv, wqkvT_ta + 512 * 512, 512, 512, 1024, 1024, 0);
  wt(ta_wo, woT_ta, 512, 512, 512, 512, 0);
  st_wtrans_geglu<<<dim3((2816 * 512) / 256), 256, 0, stream>>>(ff_win, winT, 2816L * 512);
  wt(ff_wout, woutT, 1365, 1376, 512, 512, 0);
  // 3) CPB tables
  st_cpb<<<dim3(3969), 256, 0, stream>>>(sp_w1, sp_b1, sp_w2, sp_b2, sp_w3, sp_b3, tab2f, tabf, 1);
  st_cpb<<<dim3(15), 256, 0, stream>>>(tp_w1, tp_b1, tp_w2, tp_b2, tp_w3, tp_b3, tab2f, tabf, 0);

  // ---- spatial attention ----
  st_rmsnorm<<<dim3(4096), 256, 0, stream>>>(xs, sa_gamma, xn);
  st_gemm8<1><<<dim3(64, 6), 512, 0, stream>>>(
      xn, wqkvT_sa, (void*)qkv, 16384, 1536, 512, 512, 512, 1536);
  st_vtrans<<<dim3(32, 2, 128), 256, 0, stream>>>(qkv, vT);
  st_flash<<<dim3(8, 128), 256, 0, stream>>>(qkv, vT, tab2f, ob_s);
  // wo + residual + fused spatial->temporal permute  -> xt
  st_gemm<3><<<dim3(128, 4, 1), 256, 0, stream>>>(
      ob_s, woT_sa, (void*)xt, nullptr, xs, 16384, 512, 512, 512, 512, 512);

  // ---- temporal attention ----
  st_rmsnorm<<<dim3(4096), 256, 0, stream>>>(xt, ta_gamma, xn);
  st_gemm8<1><<<dim3(64, 6), 512, 0, stream>>>(
      xn, wqkvT_ta, (void*)qkv, 16384, 1536, 512, 512, 512, 1536);
  st_tattn2<<<dim3(4096), 256, 0, stream>>>(qkv, tabf, ob_t);
  // wo + residual + fused temporal->spatial permute -> xs (f32) + xn (bf16)
  st_gemm<4><<<dim3(128, 4, 1), 256, 0, stream>>>(
      ob_t, woT_ta, (void*)xs, (void*)xn, xt, 16384, 512, 512, 512, 512, 512);

  // ---- feed-forward ----
  st_gemm8<5><<<dim3(64, 11), 512, 0, stream>>>(
      xn, winT, (void*)ybuf, 16384, 2816, 512, 512, 512, 1365);
  st_glu<<<dim3(16384), 256, 0, stream>>>(ybuf, ff_gamma, ynb);
  st_gemm<2><<<dim3(128, 4, 1), 256, 0, stream>>>(
      ynb, woutT, (void*)xs, nullptr, xs, 16384, 512, 1376, 1376, 1376, 512);

  // ---- output: per b transpose (8192 x 512) -> (512 x 8192) ----
  st_transpose2d<<<dim3(16, 256, 2), 256, 0, stream>>>(xs, outp, 8192, 512,
                                                       (long long)8192 * 512, (long long)8192 * 512);
}

// Round 5
// 654.860 us; speedup vs baseline: 1.1307x; 1.1307x over previous
//
#include <hip/hip_runtime.h>
#include <cstdint>
#include <cstddef>

typedef __bf16 bf16_t;
typedef __bf16 bf16x8 __attribute__((ext_vector_type(8)));
typedef __bf16 bf16x4 __attribute__((ext_vector_type(4)));
typedef float floatx4 __attribute__((ext_vector_type(4)));

// ---------------- helpers ----------------
__device__ __forceinline__ float wred_sum(float v) {
#pragma unroll
  for (int off = 32; off > 0; off >>= 1) v += __shfl_xor(v, off);
  return v;
}
__device__ __forceinline__ void async16(const void* g, void* l) {
  __builtin_amdgcn_global_load_lds((const __attribute__((address_space(1))) void*)g,
                                   (__attribute__((address_space(3))) void*)l, 16, 0, 0);
}

// ---------------- generic bf16 GEMM (R12: m97 shape + triple-buffer + counted vmcnt) ----------------
// R10 base (XOR chunk-swizzle, hoisted staging pointers, tanh-gelu) with the R12 change:
// 3 LDS buffers; loads for tile t issued at iter t-2; per iter ONE raw s_barrier preceded
// by s_waitcnt vmcnt(4) (counted, never 0 mid-loop). Per-thread: exactly 4 loads/iter, so
// vmcnt(4) after issuing tile t+2 -> tile t+1 retired per-thread; barrier makes it
// collective (wait-then-barrier). Buf being overwritten (t-1) was consumed before the
// previous barrier. Replaces 2x __syncthreads (full vmcnt(0) drain, m233's ~70% stall)
// with 1 counted-wait barrier at UNCHANGED occupancy (48 KB LDS -> 3 blocks/CU).
// MODE: 1 bf16 out | 2 f32 out + resid | 3 resid + spatial->temporal permuted f32 write |
//       4 resid + temporal->spatial permuted f32 write + bf16 dual write |
//       5 GeGLU epilogue (interleaved a/gate cols) -> bf16 y [M x 1365]
template <int MODE>
__global__ __launch_bounds__(256) void st_gemm(
    const bf16_t* __restrict__ A, const bf16_t* __restrict__ B, void* Cp, void* Cp2,
    const float* Res, int M, int N, int K, int lda, int ldb, int ldc) {
  __shared__ bf16_t sA[3][128 * 32];  // 24 KB
  __shared__ bf16_t sB[3][128 * 32];  // 24 KB
  const int tid = threadIdx.x;
  const int bm = blockIdx.x, bn = blockIdx.y;
  const int lane = tid & 63;
  const int wave = tid >> 6;
  const int wm = (wave >> 1) * 64, wn = (wave & 1) * 64;
  const int rowf = lane & 15, qc = lane >> 4;
  const int fco = (qc ^ ((rowf >> 1) & 3)) * 8;  // lane-constant fragment chunk (swizzled)

  // hoisted staging pointers (src pre-swizzled so LDS dest stays linear)
  const bf16_t* aSrc[2];
  const bf16_t* bSrc[2];
  int sOff[2];
#pragma unroll
  for (int it = 0; it < 2; ++it) {
    int slot = it * 256 + tid;
    int mi = slot >> 2, kc = slot & 3;
    int cs = kc ^ ((mi >> 1) & 3);
    int ar = bm * 128 + mi; if (ar > M - 1) ar = M - 1;
    int br = bn * 128 + mi; if (br > N - 1) br = N - 1;
    aSrc[it] = A + (size_t)ar * lda + cs * 8;
    bSrc[it] = B + (size_t)br * ldb + cs * 8;
    sOff[it] = slot * 16;
  }

  floatx4 acc[4][4];
#pragma unroll
  for (int i = 0; i < 4; ++i)
#pragma unroll
    for (int j = 0; j < 4; ++j) acc[i][j] = floatx4{0.f, 0.f, 0.f, 0.f};

  const int NT = K >> 5;  // requires NT >= 3 (K >= 96); all call sites have K in {512,1376}
  // prologue: stage tiles 0 and 1; certify tile 0 (vmcnt(4): tile 1 stays in flight)
#pragma unroll
  for (int it = 0; it < 2; ++it) {
    async16(aSrc[it], (char*)sA[0] + sOff[it]);
    async16(bSrc[it], (char*)sB[0] + sOff[it]);
  }
#pragma unroll
  for (int it = 0; it < 2; ++it) {
    async16(aSrc[it] + 32, (char*)sA[1] + sOff[it]);
    async16(bSrc[it] + 32, (char*)sB[1] + sOff[it]);
  }
  __builtin_amdgcn_sched_barrier(0);
  asm volatile("s_waitcnt vmcnt(4)" ::: "memory");
  __builtin_amdgcn_s_barrier();
  __builtin_amdgcn_sched_barrier(0);

  int bcur = 0, bnx = 2;
#pragma unroll 1
  for (int t = 0; t < NT; ++t) {
    const bf16_t* sAc = sA[bcur];
    const bf16_t* sBc = sB[bcur];
    bf16x8 af[4], bv[4];
#pragma unroll
    for (int i = 0; i < 4; ++i) {
      af[i] = *(const bf16x8*)(sAc + (wm + i * 16 + rowf) * 32 + fco);
      bv[i] = *(const bf16x8*)(sBc + (wn + i * 16 + rowf) * 32 + fco);
    }
    // stage tile t+2 into buf consumed at iter t-1 (safe: past its trailing barrier);
    // issued before MFMA so the loads fly under ~2 iterations of compute.
    if (t + 2 < NT) {
      const int kt2 = (t + 2) * 32;
#pragma unroll
      for (int it = 0; it < 2; ++it) {
        async16(aSrc[it] + kt2, (char*)sA[bnx] + sOff[it]);
        async16(bSrc[it] + kt2, (char*)sB[bnx] + sOff[it]);
      }
    }
#pragma unroll
    for (int i = 0; i < 4; ++i)
#pragma unroll
      for (int j = 0; j < 4; ++j)
        acc[i][j] = __builtin_amdgcn_mfma_f32_16x16x32_bf16(af[i], bv[j], acc[i][j], 0, 0, 0);
    if (t + 1 < NT) {
      __builtin_amdgcn_sched_barrier(0);
      if (t + 2 < NT) asm volatile("s_waitcnt vmcnt(4)" ::: "memory");
      else            asm volatile("s_waitcnt vmcnt(0)" ::: "memory");
      __builtin_amdgcn_s_barrier();
      __builtin_amdgcn_sched_barrier(0);
    }
    bcur = (bcur == 2) ? 0 : bcur + 1;
    bnx = (bnx == 2) ? 0 : bnx + 1;
  }

  const int cl = lane & 15;
  const int rowBase = bm * 128 + wm + (lane >> 4) * 4;
  if (MODE == 5) {
    // GeGLU: col pairs (j even = a-tile, j odd = gate-tile); tanh-form gelu
    bf16_t* yb = (bf16_t*)Cp;
    const int cg0 = ((bn * 128 + wn) >> 5) * 16;
#pragma unroll
    for (int i = 0; i < 4; ++i) {
#pragma unroll
      for (int p = 0; p < 2; ++p) {
        int c = cg0 + p * 16 + cl;
        if (c >= 1365) continue;
#pragma unroll
        for (int r = 0; r < 4; ++r) {
          int row = rowBase + i * 16 + r;
          if (row >= M) continue;
          float a = acc[i][2 * p][r];
          float gt = acc[i][2 * p + 1][r];
          float zz = gt * (0.7978845608f + 0.03567740814f * gt * gt);
          float u = __builtin_exp2f(-2.8853900817779268f * zz);
          float y = a * gt / (1.f + u);
          yb[(size_t)row * ldc + c] = (bf16_t)y;
        }
      }
    }
    return;
  }
  const int colBase = bn * 128 + wn + cl;
#pragma unroll
  for (int i = 0; i < 4; ++i) {
#pragma unroll
    for (int j = 0; j < 4; ++j) {
      int col = colBase + j * 16;
      if (col >= N) continue;
#pragma unroll
      for (int r = 0; r < 4; ++r) {
        int row = rowBase + i * 16 + r;
        if (row >= M) continue;
        long long inidx = (long long)row * ldc + col;
        float v = acc[i][j][r];
        if (MODE >= 2) v += Res[inidx];
        if (MODE == 1) { ((bf16_t*)Cp)[inidx] = (bf16_t)v; }
        else if (MODE == 2) { ((float*)Cp)[inidx] = v; }
        else if (MODE == 3) {
          int orow = (row & ~8191) | ((row & 1023) << 3) | ((row >> 10) & 7);
          ((float*)Cp)[(long long)orow * ldc + col] = v;
        } else if (MODE == 4) {
          int orow = (row & ~8191) | ((row & 7) << 10) | ((row >> 3) & 1023);
          long long oidx = (long long)orow * ldc + col;
          ((float*)Cp)[oidx] = v;
          ((bf16_t*)Cp2)[oidx] = (bf16_t)v;
        }
      }
    }
  }
}

// ---------------- tiled fp32 transpose (R x C) -> (C x R), batched ----------------
__global__ __launch_bounds__(256) void st_transpose2d(
    const float* __restrict__ in, float* __restrict__ out, int R, int Cc,
    long long inb, long long outb) {
  __shared__ float tile[32][33];
  const int ct = blockIdx.x, rt = blockIdx.y, b = blockIdx.z;
  in += (long long)b * inb;
  out += (long long)b * outb;
  const int tx = threadIdx.x & 31, ty = threadIdx.x >> 5;
#pragma unroll
  for (int k = 0; k < 4; ++k) {
    int r = rt * 32 + ty + k * 8;
    int c = ct * 32 + tx;
    tile[ty + k * 8][tx] = in[(size_t)r * Cc + c];
  }
  __syncthreads();
#pragma unroll
  for (int k = 0; k < 4; ++k) {
    int c = ct * 32 + ty + k * 8;
    int r = rt * 32 + tx;
    out[(size_t)c * R + r] = tile[tx][ty + k * 8];
  }
}

// ---------------- weight transpose fp32 (K x N) -> bf16 (N x Kpad) ----------------
__global__ void st_wtrans(const float* __restrict__ src, bf16_t* __restrict__ dst,
                          int K, int Kpad, int N, int srcld, int coloff, long total) {
  long idx = (long)blockIdx.x * 256 + threadIdx.x;
  if (idx >= total) return;
  int kp = (int)(idx % Kpad);
  int n = (int)(idx / Kpad);
  float v = (kp < K) ? src[(size_t)kp * srcld + coloff + n] : 0.f;
  dst[idx] = (bf16_t)v;
}

// winT GeGLU-interleave: dst row n: block=n>>5, w=n&31;
// c = block*16 + (w&15); a if (n>>4)&1==0 else gate (srccol += 1365); pad rows -> 0
__global__ void st_wtrans_geglu(const float* __restrict__ src, bf16_t* __restrict__ dst,
                                long total) {
  long idx = (long)blockIdx.x * 256 + threadIdx.x;
  if (idx >= total) return;
  int kp = (int)(idx & 511);
  int n = (int)(idx >> 9);
  int c = ((n >> 5) << 4) + (n & 15);
  float v = 0.f;
  if (c < 1365) {
    int srccol = c + (((n >> 4) & 1) ? 1365 : 0);
    v = src[(size_t)kp * 2730 + srccol];
  }
  dst[idx] = (bf16_t)v;
}

// ---------------- CPB MLP tables ----------------
// 2d table: f32, pre-scaled by 8 so it can serve directly as the MFMA C-init:
// exp(0.125*s + b) == exp2((s + 8b) * 0.125 * log2(e))
__global__ __launch_bounds__(256) void st_cpb(
    const float* __restrict__ w1, const float* __restrict__ b1,
    const float* __restrict__ w2, const float* __restrict__ b2,
    const float* __restrict__ w3, const float* __restrict__ b3,
    float* __restrict__ tab2d, float* __restrict__ tab1d, int two_d) {
  const int pos = blockIdx.x, t = threadIdx.x;
  float r0, r1 = 0.f;
  if (two_d) { r0 = (float)(pos / 63 - 31); r1 = (float)(pos % 63 - 31); }
  else { r0 = (float)(pos - 7); }
  __shared__ float sh[256];
  float h = r0 * w1[t] + (two_d ? r1 * w1[256 + t] : 0.f) + b1[t];
  h = h / (1.f + expf(-h));
  sh[t] = h;
  __syncthreads();
  float h2 = b2[t];
  for (int j = 0; j < 256; ++j) h2 += sh[j] * w2[j * 256 + t];
  h2 = h2 / (1.f + expf(-h2));
  __syncthreads();
  sh[t] = h2;
  __syncthreads();
  if (t < 8) {
    float o = b3[t];
    for (int j = 0; j < 256; ++j) o += sh[j] * w3[j * 8 + t];
    if (two_d) tab2d[t * 4000 + pos] = o * 8.0f;
    else tab1d[t * 15 + pos] = o;
  }
}

// ---------------- RMS norm -> bf16 ----------------
__global__ __launch_bounds__(256) void st_rmsnorm(const float* __restrict__ x,
                                                  const float* __restrict__ gamma,
                                                  bf16_t* __restrict__ y) {
  const int token = blockIdx.x * 4 + (threadIdx.x >> 6);
  const int lane = threadIdx.x & 63;
  const float* xr = x + (size_t)token * 512;
  float v[8];
  float ss = 0.f;
#pragma unroll
  for (int k = 0; k < 8; ++k) { v[k] = xr[k * 64 + lane]; ss += v[k] * v[k]; }
  ss = wred_sum(ss);
  const float r = 22.627416998f / fmaxf(sqrtf(ss), 1e-12f);
  bf16_t* yr = y + (size_t)token * 512;
#pragma unroll
  for (int k = 0; k < 8; ++k) yr[k * 64 + lane] = (bf16_t)(v[k] * r * gamma[k * 64 + lane]);
}

// ---------------- V transpose: qkv -> vT[(bf*8+h)][d][j] ----------------
__global__ __launch_bounds__(256) void st_vtrans(const bf16_t* __restrict__ qkv,
                                                 bf16_t* __restrict__ vT) {
  __shared__ float tile[32][33];
  const int jt = blockIdx.x, dt = blockIdx.y, z = blockIdx.z;
  const int bf = z >> 3, h = z & 7;
  const int tx = threadIdx.x & 31, ty = threadIdx.x >> 5;
#pragma unroll
  for (int k = 0; k < 4; ++k) {
    int j = jt * 32 + ty + k * 8;
    int d = dt * 32 + tx;
    tile[ty + k * 8][tx] = (float)qkv[((size_t)(bf * 1024 + j)) * 1536 + 1024 + h * 64 + d];
  }
  __syncthreads();
#pragma unroll
  for (int k = 0; k < 4; ++k) {
    int d = dt * 32 + ty + k * 8;
    int j = jt * 32 + tx;
    vT[((size_t)z * 64 + d) * 1024 + j] = (bf16_t)tile[tx][ty + k * 8];
  }
}

// ---------------- fused flash spatial attention (R9 structure) ----------------
__global__ __launch_bounds__(256, 4) void st_flash(
    const bf16_t* __restrict__ qkv, const bf16_t* __restrict__ vT,
    const float* __restrict__ tab2f, bf16_t* __restrict__ ob) {
  __shared__ __align__(16) bf16_t ldsK[2][32 * 64];   // [j][d] rows 128B, XOR-swz (row&7)
  __shared__ __align__(16) bf16_t ldsV[2][64 * 32];   // [d][j] rows 64B,  XOR-swz (row&3)
  __shared__ __align__(16) bf16_t ldsP[4 * 32 * 32];  // per-wave 32i x 32j, rows 64B
  __shared__ __align__(16) float ldsT[2208];          // f32 bias slice (pre-scaled x8)
  const int qtile = blockIdx.x;  // 0..7, 128 q rows each
  const int z = blockIdx.y;
  const int bf = z >> 3, h = z & 7;
  const int tid = threadIdx.x;
  const int lane = tid & 63, wave = tid >> 6;
  const int cl = lane & 15, g = lane >> 4;
  const size_t qkvBase = (size_t)bf * 1024 * 1536 + h * 64;
  const int eoff = (qtile * 252) & ~3;
  const bf16_t* Kp = qkv + qkvBase + 512;
  const bf16_t* Vp = vT + (size_t)z * 65536;

#pragma unroll
  for (int it = 0; it < 3; ++it) {
    int s = it * 256 + tid;
    if (s < 552) async16(tab2f + h * 4000 + eoff + s * 4, (char*)ldsT + s * 16);
  }
  {
    int row = tid >> 3, c = tid & 7, cs = c ^ (row & 7);
    async16(Kp + (size_t)row * 1536 + cs * 8, (char*)ldsK[0] + tid * 16);
    int rv = tid >> 2, cv = tid & 3, csv = cv ^ (rv & 3);
    async16(Vp + (size_t)rv * 1024 + csv * 8, (char*)ldsV[0] + tid * 16);
  }
  bf16x8 aq[2][2];
#pragma unroll
  for (int it = 0; it < 2; ++it)
#pragma unroll
    for (int ks = 0; ks < 2; ++ks) {
      int row = qtile * 128 + wave * 32 + it * 16 + cl;
      aq[it][ks] = *(const bf16x8*)(qkv + qkvBase + (size_t)row * 1536 + (ks * 4 + g) * 8);
    }
  __syncthreads();

  int fiB[2];
#pragma unroll
  for (int it = 0; it < 2; ++it) {
    int i = qtile * 128 + wave * 32 + it * 16 + cl;
    fiB[it] = (i >> 5) * 63 + (i & 31) + 1984 - eoff;
  }
  float lsum[2] = {0.f, 0.f};
  floatx4 oacc[4][2];
#pragma unroll
  for (int dt = 0; dt < 4; ++dt)
#pragma unroll
    for (int it = 0; it < 2; ++it) oacc[dt][it] = floatx4{0.f, 0.f, 0.f, 0.f};

  bf16_t* ldsPw = ldsP + wave * (32 * 32);
  const float SC = 0.18033688011112042f;  // 0.125 * log2(e)

#pragma unroll 2
  for (int t = 0; t < 32; ++t) {
    const int p = t & 1;
    if (t < 31) {
      const int j1 = (t + 1) * 32;
      int row = tid >> 3, c = tid & 7, cs = c ^ (row & 7);
      async16(Kp + (size_t)(j1 + row) * 1536 + cs * 8, (char*)ldsK[p ^ 1] + tid * 16);
      int rv = tid >> 2, cv = tid & 3, csv = cv ^ (rv & 3);
      async16(Vp + (size_t)rv * 1024 + j1 + csv * 8, (char*)ldsV[p ^ 1] + tid * 16);
    }
    const int j0 = t * 32;
#pragma unroll
    for (int jt = 0; jt < 2; ++jt) {
      int jb = j0 + jt * 16 + g * 4;
      int fjb = (jb >> 5) * 63 + (jb & 31);
      floatx4 sj[2];
#pragma unroll
      for (int it = 0; it < 2; ++it) {
        int idx0 = fiB[it] - fjb;
        sj[it] = floatx4{ldsT[idx0], ldsT[idx0 - 1], ldsT[idx0 - 2], ldsT[idx0 - 3]};
      }
#pragma unroll
      for (int ks = 0; ks < 2; ++ks) {
        int row = jt * 16 + cl;
        bf16x8 kf = *(const bf16x8*)(ldsK[p] + row * 64 + (((ks * 4 + g) ^ (row & 7))) * 8);
#pragma unroll
        for (int it = 0; it < 2; ++it)
          sj[it] = __builtin_amdgcn_mfma_f32_16x16x32_bf16(kf, aq[it][ks], sj[it], 0, 0, 0);
      }
      int gg = jt * 2 + (g >> 1);
#pragma unroll
      for (int it = 0; it < 2; ++it) {
        float e0 = __builtin_exp2f(sj[it][0] * SC);
        float e1 = __builtin_exp2f(sj[it][1] * SC);
        float e2 = __builtin_exp2f(sj[it][2] * SC);
        float e3 = __builtin_exp2f(sj[it][3] * SC);
        lsum[it] += (e0 + e1) + (e2 + e3);
        bf16x4 pv = {(bf16_t)e0, (bf16_t)e1, (bf16_t)e2, (bf16_t)e3};
        *(bf16x4*)((char*)ldsPw + (it * 16 + cl) * 64 +
                   ((gg ^ (cl & 3)) * 16 + (g & 1) * 8)) = pv;
      }
    }
    {
      bf16x8 pB[2];
#pragma unroll
      for (int it = 0; it < 2; ++it)
        pB[it] = *(const bf16x8*)((char*)ldsPw + (it * 16 + cl) * 64 + ((g ^ (cl & 3)) * 16));
#pragma unroll
      for (int dt = 0; dt < 4; ++dt) {
        int row = dt * 16 + cl;
        bf16x8 vf = *(const bf16x8*)(ldsV[p] + row * 32 + ((g ^ (row & 3)) * 8));
#pragma unroll
        for (int it = 0; it < 2; ++it)
          oacc[dt][it] = __builtin_amdgcn_mfma_f32_16x16x32_bf16(vf, pB[it], oacc[dt][it], 0, 0, 0);
      }
    }
    __syncthreads();
  }
  float inv[2];
#pragma unroll
  for (int it = 0; it < 2; ++it) {
    float s = lsum[it];
    s += __shfl_xor(s, 16);
    s += __shfl_xor(s, 32);
    inv[it] = 1.f / s;
  }
#pragma unroll
  for (int it = 0; it < 2; ++it) {
    int i = qtile * 128 + wave * 32 + it * 16 + cl;
    size_t base = ((size_t)bf * 1024 + i) * 512 + h * 64 + g * 4;
#pragma unroll
    for (int dt = 0; dt < 4; ++dt) {
      bf16x4 ov = {(bf16_t)(oacc[dt][it][0] * inv[it]), (bf16_t)(oacc[dt][it][1] * inv[it]),
                   (bf16_t)(oacc[dt][it][2] * inv[it]), (bf16_t)(oacc[dt][it][3] * inv[it])};
      *(bf16x4*)(ob + base + dt * 16) = ov;
    }
  }
}

// ---------------- temporal attention (seq=8), log-transpose reduce ----------------
__global__ __launch_bounds__(256) void st_tattn2(const bf16_t* __restrict__ qkv,
                                                 const float* __restrict__ tabf,
                                                 bf16_t* __restrict__ o) {
  const int wg = blockIdx.x * 4 + (threadIdx.x >> 6);
  const int bhw = wg >> 3, head = wg & 7;
  const int lane = threadIdx.x & 63;
  const size_t base = (size_t)bhw * 8 * 1536 + head * 64 + lane;
  float q[8], k[8], v[8];
#pragma unroll
  for (int f = 0; f < 8; ++f) {
    q[f] = (float)qkv[base + (size_t)f * 1536];
    k[f] = (float)qkv[base + (size_t)f * 1536 + 512];
    v[f] = (float)qkv[base + (size_t)f * 1536 + 1024];
  }
  float p[64];
#pragma unroll
  for (int i = 0; i < 8; ++i)
#pragma unroll
    for (int j = 0; j < 8; ++j) p[i * 8 + j] = q[i] * k[j];
#pragma unroll
  for (int st = 32; st >= 1; st >>= 1) {
    const bool hi = (lane & st) != 0;
#pragma unroll
    for (int m = 0; m < st; ++m) {
      float give = hi ? p[m] : p[m + st];
      float keep = hi ? p[m + st] : p[m];
      p[m] = keep + __shfl_xor(give, st);
    }
  }
  const int i = lane >> 3, j = lane & 7;
  float e = __expf(p[0] * 0.125f + tabf[head * 15 + i - j + 7]);
  float sm = e;
  sm += __shfl_xor(sm, 1);
  sm += __shfl_xor(sm, 2);
  sm += __shfl_xor(sm, 4);
  const float prob = e / sm;
  float acc[8];
#pragma unroll
  for (int ii = 0; ii < 8; ++ii) acc[ii] = 0.f;
#pragma unroll
  for (int ii = 0; ii < 8; ++ii)
#pragma unroll
    for (int jj = 0; jj < 8; ++jj)
      acc[ii] += __shfl(prob, ii * 8 + jj) * v[jj];
#pragma unroll
  for (int ii = 0; ii < 8; ++ii)
    o[(size_t)(bhw * 8 + ii) * 512 + head * 64 + lane] = (bf16_t)acc[ii];
}

// ---------------- temporal shift + RMS on pre-activated y -> ynb (K padded 1376) ----------------
__global__ __launch_bounds__(256) void st_glu(const bf16_t* __restrict__ y,
                                              const float* __restrict__ gamma,
                                              bf16_t* __restrict__ yn) {
  const int t = blockIdx.x;
  const int tid = threadIdx.x;
  const int f = (t >> 10) & 7;
  float yv[6];
  float ss = 0.f;
#pragma unroll
  for (int kk = 0; kk < 6; ++kk) {
    int c = kk * 256 + tid;
    float v = 0.f;
    if (c < 1365) {
      long src = t;
      bool valid = true;
      if (c >= 683) { if (f == 0) valid = false; else src = t - 1024; }
      if (valid) v = (float)y[src * 1365 + c];
    }
    yv[kk] = v;
    ss += v * v;
  }
  __shared__ float red[4];
  ss = wred_sum(ss);
  if ((tid & 63) == 0) red[tid >> 6] = ss;
  __syncthreads();
  ss = red[0] + red[1] + red[2] + red[3];
  const float r = sqrtf(1365.f) / fmaxf(sqrtf(ss), 1e-12f);
#pragma unroll
  for (int kk = 0; kk < 6; ++kk) {
    int c = kk * 256 + tid;
    if (c < 1365) yn[(size_t)t * 1376 + c] = (bf16_t)(yv[kk] * r * gamma[c]);
  }
  if (tid < 11) yn[(size_t)t * 1376 + 1365 + tid] = (bf16_t)0.f;
}

// ---------------- launcher ----------------
extern "C" void kernel_launch(void* const* d_in, const int* in_sizes, int n_in,
                              void* d_out, int out_size, void* d_ws, size_t ws_size,
                              hipStream_t stream) {
  const float* x        = (const float*)d_in[0];
  const float* sa_gamma = (const float*)d_in[1];
  const float* sa_wq    = (const float*)d_in[2];
  const float* sa_wkv   = (const float*)d_in[3];
  const float* sa_wo    = (const float*)d_in[4];
  const float* ta_gamma = (const float*)d_in[5];
  const float* ta_wq    = (const float*)d_in[6];
  const float* ta_wkv   = (const float*)d_in[7];
  const float* ta_wo    = (const float*)d_in[8];
  const float* sp_w1 = (const float*)d_in[9];
  const float* sp_b1 = (const float*)d_in[10];
  const float* sp_w2 = (const float*)d_in[11];
  const float* sp_b2 = (const float*)d_in[12];
  const float* sp_w3 = (const float*)d_in[13];
  const float* sp_b3 = (const float*)d_in[14];
  const float* tp_w1 = (const float*)d_in[15];
  const float* tp_b1 = (const float*)d_in[16];
  const float* tp_w2 = (const float*)d_in[17];
  const float* tp_b2 = (const float*)d_in[18];
  const float* tp_w3 = (const float*)d_in[19];
  const float* tp_b3 = (const float*)d_in[20];
  const float* ff_win   = (const float*)d_in[21];
  const float* ff_gamma = (const float*)d_in[22];
  const float* ff_wout  = (const float*)d_in[23];
  float* outp = (float*)d_out;

  char* ws = (char*)d_ws;
  size_t off = 0;
  auto alloc = [&](size_t bytes) -> char* {
    char* p = ws + off;
    off += (bytes + 255) & ~(size_t)255;
    return p;
  };
  const long T = 16384;
  float*  xs  = (float*)alloc((size_t)T * 512 * 4);    // residual stream
  bf16_t* xn  = (bf16_t*)alloc((size_t)T * 512 * 2);   // normed input | ob_s
  char*   R2  = alloc((size_t)T * 1536 * 2);           // qkv | FF: y (16384x1365 bf16)
  char*   R3  = alloc((size_t)T * 1536 * 2);           // vT (16M) | xt (33.5M)
  char*   R4  = alloc((size_t)T * 1376 * 2);           // ob_t (16M) | ynb (45M)
  bf16_t* wqkvT_sa = (bf16_t*)alloc(1536ULL * 512 * 2);
  bf16_t* woT_sa   = (bf16_t*)alloc(512ULL * 512 * 2);
  bf16_t* wqkvT_ta = (bf16_t*)alloc(1536ULL * 512 * 2);
  bf16_t* woT_ta   = (bf16_t*)alloc(512ULL * 512 * 2);
  bf16_t* winT  = (bf16_t*)alloc(2752ULL * 512 * 2);   // GeGLU-interleaved
  bf16_t* woutT = (bf16_t*)alloc(512ULL * 1376 * 2);
  float*  tab2f = (float*)alloc(8 * 4000 * 4);         // f32 spatial bias (x8 pre-scale)
  float*  tabf  = (float*)alloc(8 * 15 * 4);

  bf16_t* qkv  = (bf16_t*)R2;
  bf16_t* ybuf = (bf16_t*)R2;    // FF pre-activated hidden (qkv dead)
  bf16_t* vT   = (bf16_t*)R3;
  float*  xt   = (float*)R3;     // temporal residual (vT dead after flash)
  bf16_t* ob_s = xn;             // spatial attn out reuses xn region
  bf16_t* ob_t = (bf16_t*)R4;    // temporal attn out
  bf16_t* ynb  = (bf16_t*)R4;    // normed FF hidden (ob_t dead)

  // 1) input: per b transpose (512 x 8192) -> (8192 x 512)
  st_transpose2d<<<dim3(256, 16, 2), 256, 0, stream>>>(x, xs, 512, 8192,
                                                       (long long)512 * 8192, (long long)512 * 8192);
  // 2) weight transposes
  auto wt = [&](const float* src, bf16_t* dst, int K, int Kpad, int N, int srcld, int coloff) {
    long tot = (long)N * Kpad;
    st_wtrans<<<dim3((tot + 255) / 256), 256, 0, stream>>>(src, dst, K, Kpad, N, srcld, coloff, tot);
  };
  wt(sa_wq, wqkvT_sa, 512, 512, 512, 512, 0);
  wt(sa_wkv, wqkvT_sa + 512 * 512, 512, 512, 1024, 1024, 0);
  wt(sa_wo, woT_sa, 512, 512, 512, 512, 0);
  wt(ta_wq, wqkvT_ta, 512, 512, 512, 512, 0);
  wt(ta_wkv, wqkvT_ta + 512 * 512, 512, 512, 1024, 1024, 0);
  wt(ta_wo, woT_ta, 512, 512, 512, 512, 0);
  st_wtrans_geglu<<<dim3((2752 * 512) / 256), 256, 0, stream>>>(ff_win, winT, 2752L * 512);
  wt(ff_wout, woutT, 1365, 1376, 512, 512, 0);
  // 3) CPB tables
  st_cpb<<<dim3(3969), 256, 0, stream>>>(sp_w1, sp_b1, sp_w2, sp_b2, sp_w3, sp_b3, tab2f, tabf, 1);
  st_cpb<<<dim3(15), 256, 0, stream>>>(tp_w1, tp_b1, tp_w2, tp_b2, tp_w3, tp_b3, tab2f, tabf, 0);

  // ---- spatial attention ----
  st_rmsnorm<<<dim3(4096), 256, 0, stream>>>(xs, sa_gamma, xn);
  st_gemm<1><<<dim3(128, 12), 256, 0, stream>>>(
      xn, wqkvT_sa, (void*)qkv, nullptr, nullptr, 16384, 1536, 512, 512, 512, 1536);
  st_vtrans<<<dim3(32, 2, 128), 256, 0, stream>>>(qkv, vT);
  st_flash<<<dim3(8, 128), 256, 0, stream>>>(qkv, vT, tab2f, ob_s);
  // wo + residual + fused spatial->temporal permute  -> xt
  st_gemm<3><<<dim3(128, 4), 256, 0, stream>>>(
      ob_s, woT_sa, (void*)xt, nullptr, xs, 16384, 512, 512, 512, 512, 512);

  // ---- temporal attention ----
  st_rmsnorm<<<dim3(4096), 256, 0, stream>>>(xt, ta_gamma, xn);
  st_gemm<1><<<dim3(128, 12), 256, 0, stream>>>(
      xn, wqkvT_ta, (void*)qkv, nullptr, nullptr, 16384, 1536, 512, 512, 512, 1536);
  st_tattn2<<<dim3(4096), 256, 0, stream>>>(qkv, tabf, ob_t);
  // wo + residual + fused temporal->spatial permute -> xs (f32) + xn (bf16)
  st_gemm<4><<<dim3(128, 4), 256, 0, stream>>>(
      ob_t, woT_ta, (void*)xs, (void*)xn, xt, 16384, 512, 512, 512, 512, 512);

  // ---- feed-forward ----
  st_gemm<5><<<dim3(128, 22), 256, 0, stream>>>(
      xn, winT, (void*)ybuf, nullptr, nullptr, 16384, 2752, 512, 512, 512, 1365);
  st_glu<<<dim3(16384), 256, 0, stream>>>(ybuf, ff_gamma, ynb);
  st_gemm<2><<<dim3(128, 4), 256, 0, stream>>>(
      ynb, woutT, (void*)xs, nullptr, xs, 16384, 512, 1376, 1376, 1376, 512);

  // ---- output: per b transpose (8192 x 512) -> (512 x 8192) ----
  st_transpose2d<<<dim3(16, 256, 2), 256, 0, stream>>>(xs, outp, 8192, 512,
                                                       (long long)8192 * 512, (long long)8192 * 512);
}